// Round 1
// 249.559 us; speedup vs baseline: 1.0082x; 1.0082x over previous
//
#include <hip/hip_runtime.h>

// v10: v9 + k_deform stage-C software pipeline (prefetch distance 2 for
// sample gathers, ping-pong weight frags) + v_cvt_pk_bf16_f32 for all hot
// f32->2xbf16 pack sites. 5 dispatches.
// ws (19,415,040 B): xT/out1 8MB | raw 8MB | wTg1 1.18MB | wTg2 1.18MB |
//   wT61 72KB | wT62 72KB | pstats 128KB

typedef unsigned int u32;
typedef unsigned short u16;
typedef __attribute__((ext_vector_type(8))) short bf16x8;
typedef __attribute__((ext_vector_type(4))) float floatx4;

#define HW 4096
#define CHW 1048576

static __device__ __forceinline__ float bf2f(u16 u) {
    union { u32 i; float f; } c; c.i = ((u32)u) << 16; return c.f;
}
static __device__ __forceinline__ u16 f2bf(float f) {
    union { float f; u32 i; } c; c.f = f;
    u32 x = c.i;
    return (u16)((x + 0x7FFFu + ((x >> 16) & 1u)) >> 16);   // RNE
}
// pack two f32 -> {lo: bf16(a), hi: bf16(b)} in ONE VALU op (RNE, same as
// f2bf). No builtin on gfx950 -> inline asm.
static __device__ __forceinline__ u32 cvtpk(float a, float b) {
    u32 r;
    asm("v_cvt_pk_bf16_f32 %0, %1, %2" : "=v"(r) : "v"(a), "v"(b));
    return r;
}
static __device__ __forceinline__ float loadv(const void* p, long i, int f32) {
    return f32 ? ((const float*)p)[i] : bf2f(((const u16*)p)[i]);
}
// Inline dtype sniff: 16 fixed words of x interpreted as fp32; genuine fp32
// N(0,1) data has sane magnitudes. Wave-uniform (scalar loads).
static __device__ __forceinline__ int sniff_f32(const u32* __restrict__ xw) {
    int cnt = 0;
    #pragma unroll
    for (int s = 0; s < 16; ++s) {
        union { u32 i; float f; } c;
        c.i = xw[s * 131 + 7];
        float a = fabsf(c.f);
        if (a > 1e-8f && a < 1e4f) ++cnt;
    }
    return (cnt >= 8) ? 1 : 0;
}

// ---------------------------------------------------------------------------
// One prep kernel: blocks [0,256) NCHW->NHWC transpose (vectorized);
// [256,1408) wTg1; [1408,2560) wTg2; [2560,2704) wT61; [2704,2848) wT62.
// ---------------------------------------------------------------------------
__global__ __launch_bounds__(256) void k_prep_all(
    const void* __restrict__ x,
    const void* __restrict__ wdc1, const void* __restrict__ wdc2,
    const void* __restrict__ wtm1, const void* __restrict__ wtr1,
    const void* __restrict__ wtm2, const void* __restrict__ wtr2,
    u16* __restrict__ xT, u16* __restrict__ wTg1, u16* __restrict__ wTg2,
    u16* __restrict__ wT61, u16* __restrict__ wT62)
{
    __shared__ u16 T[64 * 258];
    const int f32 = sniff_f32((const u32*)x);
    const int b = blockIdx.x;
    const int tid = threadIdx.x;

    if (b < 256) {                       // ---- NCHW -> NHWC (LDS transpose)
        const int n = b >> 6, h = b & 63;
        const long sb = (long)n * CHW + (h << 6);
        const int cb = tid >> 3;         // 0..31
        const int w0 = (tid & 7) << 3;   // 0..56
        if (f32) {
            const float* xp = (const float*)x;
            for (int it = 0; it < 8; ++it) {
                int c = (it << 5) + cb;
                const float* pr = xp + sb + (long)c * HW + w0;
                float4 a = ((const float4*)pr)[0];
                float4 d = ((const float4*)pr)[1];
                T[(w0 + 0) * 258 + c] = f2bf(a.x);
                T[(w0 + 1) * 258 + c] = f2bf(a.y);
                T[(w0 + 2) * 258 + c] = f2bf(a.z);
                T[(w0 + 3) * 258 + c] = f2bf(a.w);
                T[(w0 + 4) * 258 + c] = f2bf(d.x);
                T[(w0 + 5) * 258 + c] = f2bf(d.y);
                T[(w0 + 6) * 258 + c] = f2bf(d.z);
                T[(w0 + 7) * 258 + c] = f2bf(d.w);
            }
        } else {
            const u16* xp = (const u16*)x;
            for (int it = 0; it < 8; ++it) {
                int c = (it << 5) + cb;
                uint4 v = *(const uint4*)(xp + sb + (long)c * HW + w0);
                u32 ws[4] = {v.x, v.y, v.z, v.w};
                #pragma unroll
                for (int q = 0; q < 4; ++q) {
                    T[(w0 + 2 * q + 0) * 258 + c] = (u16)(ws[q] & 0xFFFFu);
                    T[(w0 + 2 * q + 1) * 258 + c] = (u16)(ws[q] >> 16);
                }
            }
        }
        __syncthreads();
        const int w = tid >> 2, cq = tid & 3;
        const u32* Tr = (const u32*)T;
        u16* ob = xT + (long)n * CHW + (long)((h << 6) + w) * 256 + cq * 64;
        #pragma unroll
        for (int s = 0; s < 8; ++s) {
            uint4 o;
            o.x = Tr[129 * w + 32 * cq + 4 * s + 0];
            o.y = Tr[129 * w + 32 * cq + 4 * s + 1];
            o.z = Tr[129 * w + 32 * cq + 4 * s + 2];
            o.w = Tr[129 * w + 32 * cq + 4 * s + 3];
            *(uint4*)&ob[s * 8] = o;
        }
    } else if (b < 2560) {               // ---- deform weights (both rounds)
        const int r2 = (b >= 1408);
        const void* wdc = r2 ? wdc2 : wdc1;
        u16* wTg = r2 ? wTg2 : wTg1;
        int idx2 = (b - (r2 ? 1408 : 256)) * 256 + tid;   // 0..294911
        int cp = idx2 & 15;
        int o  = (idx2 >> 4) & 255;
        int q  = idx2 >> 12;
        int k  = q >> 3;
        int c0 = ((q & 7) << 5) + (cp << 1);
        long s0 = (long)o * 2304 + c0 * 9 + k;
        ((u32*)wTg)[idx2] = cvtpk(loadv(wdc, s0, f32), loadv(wdc, s0 + 9, f32));
    } else {                             // ---- offset-conv weights
        const int r2 = (b >= 2704);
        const void* wtm = r2 ? wtm2 : wtm1;
        const void* wtr = r2 ? wtr2 : wtr1;
        u16* wT6 = r2 ? wT62 : wT61;
        int i = (b - (r2 ? 2704 : 2560)) * 256 + tid;     // 0..36863
        int q  = i >> 9;
        int o  = (i >> 5) & 15;
        int cc = i & 31;
        int k  = q >> 3;
        int c  = ((q & 7) << 5) + cc;
        float v = 0.f;
        if (o < 4)      v = loadv(wtm, (long)o * 2304 + c * 9 + k, f32);
        else if (o < 6) v = loadv(wtr, (long)(o - 4) * 2304 + c * 9 + k, f32);
        wT6[i] = f2bf(v);
    }
}

// ---------------------------------------------------------------------------
// Mega deform: per (n,h,half) block:
//   Stage A: offset conv (MFMA) -> tmtr slice in LDS
//   Stage B: build_offset geometry
//   Stage C: barriered K-loop, SW-pipelined (prefetch dist 2), A-frags from L2
//   Stage D: GN partials -> pstats[bid][64] (plain stores, no atomics)
//   Stage E: raw (NCHW bf16) stores
// ---------------------------------------------------------------------------
__global__ __launch_bounds__(512, 4) void k_deform(
    const u16* __restrict__ srcT, const u16* __restrict__ wTg,
    const u16* __restrict__ wT6,
    const void* __restrict__ b_tm, const void* __restrict__ b_tr,
    const u32* __restrict__ xw,
    u16* __restrict__ raw, float* __restrict__ pstats)
{
    __shared__ float red[8][32][17];                 // 17408 B (stage A)
    __shared__ float tl[6 * 32];                     //   768 B
    __shared__ __align__(16) short Sl[2][32 * 40];   //  5120 B
    __shared__ int   g_y0[288];
    __shared__ int   g_x0[288];
    __shared__ float g_wy[288];
    __shared__ float g_wx[288];

    const int tid = threadIdx.x;
    const int bid = blockIdx.x;                 // n*128 + h*2 + half
    const int n = bid >> 7, h = (bid >> 1) & 63, half = bid & 1;
    const int wb = half << 5;
    const int lane = tid & 63;
    const int quad = lane >> 4;
    const int l16  = lane & 15;
    const int wv   = tid >> 6;
    const long nbase = (long)n * CHW;
    const u16* sp = srcT + nbase;

    // ---- Stage A: offset conv, 6 out-ch x 32 px ----
    {
        floatx4 acc6[2];
        acc6[0] = (floatx4){0.f, 0.f, 0.f, 0.f};
        acc6[1] = (floatx4){0.f, 0.f, 0.f, 0.f};
        for (int qi = 0; qi < 9; ++qi) {
            const int q = wv * 9 + qi;
            const int k = q >> 3, cb = q & 7;
            const int ky = k / 3, kx = k % 3;
            const int row = h + ky - 1;
            const bool rv = (row >= 0) && (row < 64);
            bf16x8 av = *(const bf16x8*)&wT6[(((q << 4) + l16) << 5) + (quad << 3)];
            #pragma unroll
            for (int j = 0; j < 2; ++j) {
                int psrc = wb + (j << 4) + l16 + kx - 1;
                bf16x8 bv = {0, 0, 0, 0, 0, 0, 0, 0};
                if (rv && psrc >= 0 && psrc < 64)
                    bv = *(const bf16x8*)&sp[(((long)(row << 6) + psrc) << 8) + (cb << 5) + (quad << 3)];
                acc6[j] = __builtin_amdgcn_mfma_f32_16x16x32_bf16(av, bv, acc6[j], 0, 0, 0);
            }
        }
        #pragma unroll
        for (int j = 0; j < 2; ++j)
            #pragma unroll
            for (int r = 0; r < 4; ++r)
                red[wv][(j << 4) + l16][(quad << 2) + r] = acc6[j][r];
        __syncthreads();
        if (tid < 192) {
            const int o = tid >> 5, px = tid & 31;
            float s = 0.f;
            #pragma unroll
            for (int v = 0; v < 8; ++v) s += red[v][px][o];
            const int f32 = sniff_f32(xw);
            float bias = (o < 4) ? loadv(b_tm, o, f32) : loadv(b_tr, o - 4, f32);
            tl[o * 32 + px] = s + bias;
        }
        __syncthreads();
    }

    // ---- Stage B: geometry for 9 taps x 32 px ----
    for (int i = tid; i < 288; i += 512) {
        int k = i >> 5, ww2 = i & 31;
        float m00 = tl[ww2],       m01 = tl[32 + ww2];
        float m10 = tl[64 + ww2],  m11 = tl[96 + ww2];
        float tr0 = tl[128 + ww2], tr1 = tl[160 + ww2];
        float ry = (float)(k / 3) - 1.f;
        float rx = (float)(k % 3) - 1.f;
        float dy = m00 * ry + m01 * rx - ry + tr0;
        float dx = m10 * ry + m11 * rx - rx + tr1;
        float py = (float)h + ry + dy;
        float px = (float)(wb + ww2) + rx + dx;
        float y0f = floorf(py), x0f = floorf(px);
        g_y0[i] = (int)y0f; g_x0[i] = (int)x0f;
        g_wy[i] = py - y0f; g_wx[i] = px - x0f;
    }
    __syncthreads();

    // ---- Stage C: main K-loop (SW pipeline, prefetch distance 2) ----
    const int sw  = tid >> 4;      // px 0..31
    const int scq = tid & 15;      // channel pair
    const int o0  = wv << 5;

    floatx4 acc[2][2];
    #pragma unroll
    for (int i = 0; i < 2; ++i)
        #pragma unroll
        for (int j = 0; j < 2; ++j)
            acc[i][j] = (floatx4){0.f, 0.f, 0.f, 0.f};

    // load-side state (addresses for gather)
    int ld_k = -1;
    int a00 = 0, a01 = 0, a10 = 0, a11 = 0;
    // publish-side state (bilinear weights)
    int pb_k = -1;
    float cw00 = 0.f, cw01 = 0.f, cw10 = 0.f, cw11 = 0.f;

    auto ld_addr = [&](int k) {
        int gi = (k << 5) + sw;
        int y0 = g_y0[gi], x0 = g_x0[gi];
        int yc0 = min(max(y0, 0), 63),     yc1 = min(max(y0 + 1, 0), 63);
        int xc0 = min(max(x0, 0), 63),     xc1 = min(max(x0 + 1, 0), 63);
        a00 = yc0 * 64 + xc0; a01 = yc0 * 64 + xc1;
        a10 = yc1 * 64 + xc0; a11 = yc1 * 64 + xc1;
    };
    auto pb_w = [&](int k) {
        int gi = (k << 5) + sw;
        int y0 = g_y0[gi], x0 = g_x0[gi];
        float wy1 = g_wy[gi], wx1 = g_wx[gi];
        float wy0 = 1.f - wy1, wx0 = 1.f - wx1;
        bool yv0 = (y0 >= 0) && (y0 < 64);
        bool yv1 = (y0 >= -1) && (y0 < 63);
        bool xv0 = (x0 >= 0) && (x0 < 64);
        bool xv1 = (x0 >= -1) && (x0 < 63);
        cw00 = (yv0 && xv0) ? wy0 * wx0 : 0.f;
        cw01 = (yv0 && xv1) ? wy0 * wx1 : 0.f;
        cw10 = (yv1 && xv0) ? wy1 * wx0 : 0.f;
        cw11 = (yv1 && xv1) ? wy1 * wx1 : 0.f;
    };
    // issue the 4 gather loads for K-step q (consumed ~1.5 iterations later)
    auto smp = [&](int q, u32& r00, u32& r01, u32& r10, u32& r11) {
        int k = q >> 3;
        if (k != ld_k) { ld_k = k; ld_addr(k); }
        const int cc = ((q & 7) << 5) + (scq << 1);
        r00 = *(const u32*)&sp[(long)a00 * 256 + cc];
        r01 = *(const u32*)&sp[(long)a01 * 256 + cc];
        r10 = *(const u32*)&sp[(long)a10 * 256 + cc];
        r11 = *(const u32*)&sp[(long)a11 * 256 + cc];
    };
    auto wload = [&](int q, bf16x8& W0, bf16x8& W1) {
        const u16* wp = wTg + (((size_t)q * 256 + o0 + l16) << 5) + (quad << 3);
        W0 = *(const bf16x8*)wp;
        W1 = *(const bf16x8*)(wp + (16 << 5));
    };
    // bilinear combine + bf16 pack (one v_cvt_pk_bf16_f32) + LDS publish
    auto pub = [&](int q, int b, u32 r00, u32 r01, u32 r10, u32 r11) {
        int k = q >> 3;
        if (k != pb_k) { pb_k = k; pb_w(k); }
        float va = fmaf(cw00, bf2f((u16)r00),
                   fmaf(cw01, bf2f((u16)r01),
                   fmaf(cw10, bf2f((u16)r10), cw11 * bf2f((u16)r11))));
        float vb = fmaf(cw00, bf2f((u16)(r00 >> 16)),
                   fmaf(cw01, bf2f((u16)(r01 >> 16)),
                   fmaf(cw10, bf2f((u16)(r10 >> 16)), cw11 * bf2f((u16)(r11 >> 16)))));
        *(u32*)&Sl[b][sw * 40 + (scq << 1)] = cvtpk(va, vb);
    };
    auto mfma4 = [&](int b, bf16x8 W0, bf16x8 W1) {
        #pragma unroll
        for (int j = 0; j < 2; ++j) {
            bf16x8 bv = *(const bf16x8*)&Sl[b][((j << 4) + l16) * 40 + (quad << 3)];
            acc[0][j] = __builtin_amdgcn_mfma_f32_16x16x32_bf16(W0, bv, acc[0][j], 0, 0, 0);
            acc[1][j] = __builtin_amdgcn_mfma_f32_16x16x32_bf16(W1, bv, acc[1][j], 0, 0, 0);
        }
    };

    // pipeline registers: two gather sets (SA/SB), two weight sets (WA/WB)
    u32 sA0, sA1, sA2, sA3, sB0, sB1, sB2, sB3;
    bf16x8 WA0, WA1, WB0, WB1;

    smp(0, sA0, sA1, sA2, sA3);        // SA <- q=0
    smp(1, sB0, sB1, sB2, sB3);        // SB <- q=1
    wload(0, WA0, WA1);                // WA <- w(0)
    wload(1, WB0, WB1);                // WB <- w(1)
    pub(0, 0, sA0, sA1, sA2, sA3);     // Sl[0] <- q=0 (SA now free)
    __syncthreads();

    // invariant entering even sub-iter q: SA free, SB=data(q+1),
    //   WA=w(q), WB=w(q+1), Sl[q&1]=published(q)
    for (int q = 0; q < 72; q += 2) {
        // --- sub-iter q (even) ---
        if (q + 2 < 72) smp(q + 2, sA0, sA1, sA2, sA3);
        mfma4(0, WA0, WA1);
        pub(q + 1, 1, sB0, sB1, sB2, sB3);          // q+1 <= 71 always
        if (q + 2 < 72) wload(q + 2, WA0, WA1);
        __syncthreads();

        // --- sub-iter q+1 (odd) ---
        if (q + 3 < 72) smp(q + 3, sB0, sB1, sB2, sB3);
        mfma4(1, WB0, WB1);
        if (q + 2 < 72) pub(q + 2, 0, sA0, sA1, sA2, sA3);
        if (q + 3 < 72) wload(q + 3, WB0, WB1);
        __syncthreads();
    }

    // ---- Stage D: GN partials (no atomics) ----
    #pragma unroll
    for (int i = 0; i < 2; ++i) {
        float s1 = 0.f, s2 = 0.f;
        #pragma unroll
        for (int j = 0; j < 2; ++j)
            #pragma unroll
            for (int r = 0; r < 4; ++r) {
                float v = acc[i][j][r];
                s1 += v; s2 += v * v;
            }
        #pragma unroll
        for (int off = 1; off <= 16; off <<= 1) {
            s1 += __shfl_xor(s1, off, 64);
            s2 += __shfl_xor(s2, off, 64);
        }
        if ((lane & 31) == 0) {
            int g = (o0 >> 3) + 2 * i + (lane >> 5);
            pstats[((long)bid << 6) + (g << 1)]     = s1;
            pstats[((long)bid << 6) + (g << 1) + 1] = s2;
        }
    }

    // ---- Stage E: raw stores ----
    #pragma unroll
    for (int i = 0; i < 2; ++i)
        #pragma unroll
        for (int j = 0; j < 2; ++j)
            #pragma unroll
            for (int r = 0; r < 4; ++r) {
                int o = o0 + i * 16 + quad * 4 + r;
                raw[nbase + ((long)o << 12) + (h << 6) + wb + (j << 4) + l16]
                    = f2bf(acc[i][j][r]);
            }
}

// ---------------------------------------------------------------------------
// GN + relu; reduces pstats, raw NCHW -> out1 NHWC (vectorized loads).
// ---------------------------------------------------------------------------
__global__ __launch_bounds__(256) void k_gn_relu(
    const u16* __restrict__ raw, const float* __restrict__ pstats,
    const void* __restrict__ gamma, const void* __restrict__ beta,
    const u32* __restrict__ xw,
    u16* __restrict__ out1)
{
    __shared__ u16 T[64 * 258];
    __shared__ float sred[4][64];
    __shared__ float sl[64];
    const int f32 = sniff_f32(xw);
    const int bid = blockIdx.x;
    const int n = bid >> 6, h = bid & 63;
    const int tid = threadIdx.x;

    {   // reduce partials: value v over 128 blocks of this n
        const int v = tid & 63, part = tid >> 6;
        float a = 0.f;
        for (int j = part * 32; j < part * 32 + 32; ++j)
            a += pstats[(((long)n * 128 + j) << 6) + v];
        sred[part][v] = a;
        __syncthreads();
        if (tid < 64) sl[tid] = sred[0][tid] + sred[1][tid] + sred[2][tid] + sred[3][tid];
        __syncthreads();
    }

    const u16* rb = raw + (long)n * CHW + (h << 6);
    const int cb = tid >> 3;         // 0..31
    const int w0 = (tid & 7) << 3;   // 0..56
    for (int it = 0; it < 8; ++it) {
        int c = (it << 5) + cb;
        int g = c >> 3;
        float mean = sl[g * 2] * (1.f / 32768.f);
        float var  = sl[g * 2 + 1] * (1.f / 32768.f) - mean * mean;
        float rstd = rsqrtf(var + 1e-5f);
        float ga = loadv(gamma, c, f32) * rstd;
        float be = loadv(beta, c, f32) - mean * ga;
        uint4 v = *(const uint4*)(rb + (long)c * HW + w0);
        u32 ws[4] = {v.x, v.y, v.z, v.w};
        #pragma unroll
        for (int q = 0; q < 4; ++q) {
            float a = fmaxf(fmaf(bf2f((u16)(ws[q] & 0xFFFFu)), ga, be), 0.f);
            float b = fmaxf(fmaf(bf2f((u16)(ws[q] >> 16)),     ga, be), 0.f);
            T[(w0 + 2 * q + 0) * 258 + c] = f2bf(a);
            T[(w0 + 2 * q + 1) * 258 + c] = f2bf(b);
        }
    }
    __syncthreads();
    const int w = tid >> 2, cq = tid & 3;
    const u32* Tr = (const u32*)T;
    u16* ob = out1 + (long)n * CHW + (long)((h << 6) + w) * 256 + cq * 64;
    #pragma unroll
    for (int s = 0; s < 8; ++s) {
        uint4 o;
        o.x = Tr[129 * w + 32 * cq + 4 * s + 0];
        o.y = Tr[129 * w + 32 * cq + 4 * s + 1];
        o.z = Tr[129 * w + 32 * cq + 4 * s + 2];
        o.w = Tr[129 * w + 32 * cq + 4 * s + 3];
        *(uint4*)&ob[s * 8] = o;
    }
}

// ---------------------------------------------------------------------------
// Final GN + residual + relu (per-block partial reduction).
// ---------------------------------------------------------------------------
__global__ __launch_bounds__(256) void k_gn_final(
    const u16* __restrict__ raw, const float* __restrict__ pstats,
    const void* __restrict__ gamma, const void* __restrict__ beta,
    const void* __restrict__ x,
    void* __restrict__ outp)
{
    __shared__ float rr[256];
    const int f32 = sniff_f32((const u32*)x);
    const int tid = threadIdx.x;
    const long e0 = ((long)blockIdx.x) << 11;
    const int n = (int)(e0 >> 20);
    const int c0 = (int)((e0 >> 12) & 255);
    const int g = c0 >> 3;

    {
        int j = tid & 127, sv = tid >> 7;
        rr[tid] = pstats[(((long)n * 128 + j) << 6) + (g << 1) + sv];
        __syncthreads();
        #pragma unroll
        for (int s = 64; s >= 1; s >>= 1) {
            if ((tid & 127) < s) rr[tid] += rr[tid + s];
            __syncthreads();
        }
    }
    float mean = rr[0] * (1.f / 32768.f);
    float var  = rr[128] * (1.f / 32768.f) - mean * mean;
    float rstd = rsqrtf(var + 1e-5f);

    const long i = blockIdx.x * 256 + tid;
    const long e = i << 3;
    const int c = (int)((e >> 12) & 255);
    float ga = loadv(gamma, c, f32) * rstd;
    float be = loadv(beta, c, f32) - mean * ga;
    uint4 p = ((const uint4*)raw)[i];
    u32 ww[4] = {p.x, p.y, p.z, p.w};
    float v[8];
    #pragma unroll
    for (int q = 0; q < 4; ++q) {
        v[2 * q + 0] = fmaxf(fmaf(bf2f((u16)(ww[q] & 0xFFFFu)), ga, be) + loadv(x, e + 2 * q + 0, f32), 0.f);
        v[2 * q + 1] = fmaxf(fmaf(bf2f((u16)(ww[q] >> 16)),     ga, be) + loadv(x, e + 2 * q + 1, f32), 0.f);
    }
    if (f32) {
        float4* op = (float4*)((float*)outp + e);
        op[0] = make_float4(v[0], v[1], v[2], v[3]);
        op[1] = make_float4(v[4], v[5], v[6], v[7]);
    } else {
        uint4 o;
        o.x = cvtpk(v[0], v[1]);
        o.y = cvtpk(v[2], v[3]);
        o.z = cvtpk(v[4], v[5]);
        o.w = cvtpk(v[6], v[7]);
        ((uint4*)outp)[i] = o;
    }
}

extern "C" void kernel_launch(void* const* d_in, const int* in_sizes, int n_in,
                              void* d_out, int out_size, void* d_ws, size_t ws_size,
                              hipStream_t stream) {
    const void* x     = d_in[0];
    const void* w_tm1 = d_in[1];
    const void* b_tm1 = d_in[2];
    const void* w_tr1 = d_in[3];
    const void* b_tr1 = d_in[4];
    const void* w_dc1 = d_in[5];
    const void* g1    = d_in[6];
    const void* be1   = d_in[7];
    const void* w_tm2 = d_in[8];
    const void* b_tm2 = d_in[9];
    const void* w_tr2 = d_in[10];
    const void* b_tr2 = d_in[11];
    const void* w_dc2 = d_in[12];
    const void* g2    = d_in[13];
    const void* be2   = d_in[14];

    char* wsb = (char*)d_ws;
    u16*   xT     = (u16*)wsb;                       // 8,388,608 (alias out1)
    u16*   raw    = (u16*)(wsb + 8388608);           // 8,388,608
    u16*   wTg1   = (u16*)(wsb + 16777216);          // 1,179,648
    u16*   wTg2   = (u16*)(wsb + 17956864);          // 1,179,648
    u16*   wT61   = (u16*)(wsb + 19136512);          //    73,728
    u16*   wT62   = (u16*)(wsb + 19210240);          //    73,728
    float* pstats = (float*)(wsb + 19283968);        //   131,072
    u16*   out1   = xT;
    const u32* xw = (const u32*)x;

    k_prep_all<<<2848, 256, 0, stream>>>(x, w_dc1, w_dc2, w_tm1, w_tr1, w_tm2, w_tr2,
                                         xT, wTg1, wTg2, wT61, wT62);
    // ---- round 1 ----
    k_deform  <<<512, 512, 0, stream>>>(xT, wTg1, wT61, b_tm1, b_tr1, xw, raw, pstats);
    k_gn_relu <<<256, 256, 0, stream>>>(raw, pstats, g1, be1, xw, out1);
    // ---- round 2 ----
    k_deform  <<<512, 512, 0, stream>>>(out1, wTg2, wT62, b_tm2, b_tr2, xw, raw, pstats);
    k_gn_final<<<2048, 256, 0, stream>>>(raw, pstats, g2, be2, x, d_out);
}

// Round 2
// 236.795 us; speedup vs baseline: 1.0625x; 1.0539x over previous
//
#include <hip/hip_runtime.h>

// v11: stage-C rebuilt as k-outer x 8-unrolled inner:
//  - TRUE deep pipeline: 4 rotating gather sets (issue s+3, consume s+2),
//    4 rotating weight slots (distance 2, no reg copies)
//  - gathers: per-k pointer bases + immediate offsets (cb*64B)
//  - weights: wave-uniform SGPR-stepped base + per-lane VGPR offset (SADDR)
//  - B-frag ds_reads at step top, MFMA at bottom (pub VALU hides lgkm)
// Rest identical to v10. 5 dispatches.
// ws (19,415,040 B): xT/out1 8MB | raw 8MB | wTg1 1.18MB | wTg2 1.18MB |
//   wT61 72KB | wT62 72KB | pstats 128KB

typedef unsigned int u32;
typedef unsigned short u16;
typedef __attribute__((ext_vector_type(8))) short bf16x8;
typedef __attribute__((ext_vector_type(4))) float floatx4;

#define HW 4096
#define CHW 1048576

static __device__ __forceinline__ float bf2f(u16 u) {
    union { u32 i; float f; } c; c.i = ((u32)u) << 16; return c.f;
}
static __device__ __forceinline__ u16 f2bf(float f) {
    union { float f; u32 i; } c; c.f = f;
    u32 x = c.i;
    return (u16)((x + 0x7FFFu + ((x >> 16) & 1u)) >> 16);   // RNE
}
// pack two f32 -> {lo: bf16(a), hi: bf16(b)} in ONE VALU op (RNE).
static __device__ __forceinline__ u32 cvtpk(float a, float b) {
    u32 r;
    asm("v_cvt_pk_bf16_f32 %0, %1, %2" : "=v"(r) : "v"(a), "v"(b));
    return r;
}
static __device__ __forceinline__ float loadv(const void* p, long i, int f32) {
    return f32 ? ((const float*)p)[i] : bf2f(((const u16*)p)[i]);
}
static __device__ __forceinline__ int sniff_f32(const u32* __restrict__ xw) {
    int cnt = 0;
    #pragma unroll
    for (int s = 0; s < 16; ++s) {
        union { u32 i; float f; } c;
        c.i = xw[s * 131 + 7];
        float a = fabsf(c.f);
        if (a > 1e-8f && a < 1e4f) ++cnt;
    }
    return (cnt >= 8) ? 1 : 0;
}

// ---------------------------------------------------------------------------
// One prep kernel: blocks [0,256) NCHW->NHWC transpose (vectorized);
// [256,1408) wTg1; [1408,2560) wTg2; [2560,2704) wT61; [2704,2848) wT62.
// ---------------------------------------------------------------------------
__global__ __launch_bounds__(256) void k_prep_all(
    const void* __restrict__ x,
    const void* __restrict__ wdc1, const void* __restrict__ wdc2,
    const void* __restrict__ wtm1, const void* __restrict__ wtr1,
    const void* __restrict__ wtm2, const void* __restrict__ wtr2,
    u16* __restrict__ xT, u16* __restrict__ wTg1, u16* __restrict__ wTg2,
    u16* __restrict__ wT61, u16* __restrict__ wT62)
{
    __shared__ u16 T[64 * 258];
    const int f32 = sniff_f32((const u32*)x);
    const int b = blockIdx.x;
    const int tid = threadIdx.x;

    if (b < 256) {                       // ---- NCHW -> NHWC (LDS transpose)
        const int n = b >> 6, h = b & 63;
        const long sb = (long)n * CHW + (h << 6);
        const int cb = tid >> 3;         // 0..31
        const int w0 = (tid & 7) << 3;   // 0..56
        if (f32) {
            const float* xp = (const float*)x;
            for (int it = 0; it < 8; ++it) {
                int c = (it << 5) + cb;
                const float* pr = xp + sb + (long)c * HW + w0;
                float4 a = ((const float4*)pr)[0];
                float4 d = ((const float4*)pr)[1];
                T[(w0 + 0) * 258 + c] = f2bf(a.x);
                T[(w0 + 1) * 258 + c] = f2bf(a.y);
                T[(w0 + 2) * 258 + c] = f2bf(a.z);
                T[(w0 + 3) * 258 + c] = f2bf(a.w);
                T[(w0 + 4) * 258 + c] = f2bf(d.x);
                T[(w0 + 5) * 258 + c] = f2bf(d.y);
                T[(w0 + 6) * 258 + c] = f2bf(d.z);
                T[(w0 + 7) * 258 + c] = f2bf(d.w);
            }
        } else {
            const u16* xp = (const u16*)x;
            for (int it = 0; it < 8; ++it) {
                int c = (it << 5) + cb;
                uint4 v = *(const uint4*)(xp + sb + (long)c * HW + w0);
                u32 ws[4] = {v.x, v.y, v.z, v.w};
                #pragma unroll
                for (int q = 0; q < 4; ++q) {
                    T[(w0 + 2 * q + 0) * 258 + c] = (u16)(ws[q] & 0xFFFFu);
                    T[(w0 + 2 * q + 1) * 258 + c] = (u16)(ws[q] >> 16);
                }
            }
        }
        __syncthreads();
        const int w = tid >> 2, cq = tid & 3;
        const u32* Tr = (const u32*)T;
        u16* ob = xT + (long)n * CHW + (long)((h << 6) + w) * 256 + cq * 64;
        #pragma unroll
        for (int s = 0; s < 8; ++s) {
            uint4 o;
            o.x = Tr[129 * w + 32 * cq + 4 * s + 0];
            o.y = Tr[129 * w + 32 * cq + 4 * s + 1];
            o.z = Tr[129 * w + 32 * cq + 4 * s + 2];
            o.w = Tr[129 * w + 32 * cq + 4 * s + 3];
            *(uint4*)&ob[s * 8] = o;
        }
    } else if (b < 2560) {               // ---- deform weights (both rounds)
        const int r2 = (b >= 1408);
        const void* wdc = r2 ? wdc2 : wdc1;
        u16* wTg = r2 ? wTg2 : wTg1;
        int idx2 = (b - (r2 ? 1408 : 256)) * 256 + tid;   // 0..294911
        int cp = idx2 & 15;
        int o  = (idx2 >> 4) & 255;
        int q  = idx2 >> 12;
        int k  = q >> 3;
        int c0 = ((q & 7) << 5) + (cp << 1);
        long s0 = (long)o * 2304 + c0 * 9 + k;
        ((u32*)wTg)[idx2] = cvtpk(loadv(wdc, s0, f32), loadv(wdc, s0 + 9, f32));
    } else {                             // ---- offset-conv weights
        const int r2 = (b >= 2704);
        const void* wtm = r2 ? wtm2 : wtm1;
        const void* wtr = r2 ? wtr2 : wtr1;
        u16* wT6 = r2 ? wT62 : wT61;
        int i = (b - (r2 ? 2704 : 2560)) * 256 + tid;     // 0..36863
        int q  = i >> 9;
        int o  = (i >> 5) & 15;
        int cc = i & 31;
        int k  = q >> 3;
        int c  = ((q & 7) << 5) + cc;
        float v = 0.f;
        if (o < 4)      v = loadv(wtm, (long)o * 2304 + c * 9 + k, f32);
        else if (o < 6) v = loadv(wtr, (long)(o - 4) * 2304 + c * 9 + k, f32);
        wT6[i] = f2bf(v);
    }
}

// ---------------------------------------------------------------------------
// Mega deform: per (n,h,half) block:
//   Stage A: offset conv (MFMA) -> tmtr slice in LDS
//   Stage B: build_offset geometry
//   Stage C: deep-pipelined K-loop (see header)
//   Stage D: GN partials -> pstats[bid][64]
//   Stage E: raw (NCHW bf16) stores
// ---------------------------------------------------------------------------
__global__ __launch_bounds__(512, 4) void k_deform(
    const u16* __restrict__ srcT, const u16* __restrict__ wTg,
    const u16* __restrict__ wT6,
    const void* __restrict__ b_tm, const void* __restrict__ b_tr,
    const u32* __restrict__ xw,
    u16* __restrict__ raw, float* __restrict__ pstats)
{
    __shared__ float red[8][32][17];                 // 17408 B (stage A)
    __shared__ float tl[6 * 32];                     //   768 B
    __shared__ __align__(16) short Sl[2][32 * 40];   //  5120 B
    __shared__ int   g_y0[288];
    __shared__ int   g_x0[288];
    __shared__ float g_wy[288];
    __shared__ float g_wx[288];

    const int tid = threadIdx.x;
    const int bid = blockIdx.x;                 // n*128 + h*2 + half
    const int n = bid >> 7, h = (bid >> 1) & 63, half = bid & 1;
    const int wb = half << 5;
    const int lane = tid & 63;
    const int quad = lane >> 4;
    const int l16  = lane & 15;
    const int wv   = tid >> 6;
    const long nbase = (long)n * CHW;
    const u16* sp = srcT + nbase;

    // ---- Stage A: offset conv, 6 out-ch x 32 px ----
    {
        floatx4 acc6[2];
        acc6[0] = (floatx4){0.f, 0.f, 0.f, 0.f};
        acc6[1] = (floatx4){0.f, 0.f, 0.f, 0.f};
        for (int qi = 0; qi < 9; ++qi) {
            const int q = wv * 9 + qi;
            const int k = q >> 3, cb = q & 7;
            const int ky = k / 3, kx = k % 3;
            const int row = h + ky - 1;
            const bool rv = (row >= 0) && (row < 64);
            bf16x8 av = *(const bf16x8*)&wT6[(((q << 4) + l16) << 5) + (quad << 3)];
            #pragma unroll
            for (int j = 0; j < 2; ++j) {
                int psrc = wb + (j << 4) + l16 + kx - 1;
                bf16x8 bv = {0, 0, 0, 0, 0, 0, 0, 0};
                if (rv && psrc >= 0 && psrc < 64)
                    bv = *(const bf16x8*)&sp[(((long)(row << 6) + psrc) << 8) + (cb << 5) + (quad << 3)];
                acc6[j] = __builtin_amdgcn_mfma_f32_16x16x32_bf16(av, bv, acc6[j], 0, 0, 0);
            }
        }
        #pragma unroll
        for (int j = 0; j < 2; ++j)
            #pragma unroll
            for (int r = 0; r < 4; ++r)
                red[wv][(j << 4) + l16][(quad << 2) + r] = acc6[j][r];
        __syncthreads();
        if (tid < 192) {
            const int o = tid >> 5, px = tid & 31;
            float s = 0.f;
            #pragma unroll
            for (int v = 0; v < 8; ++v) s += red[v][px][o];
            const int f32 = sniff_f32(xw);
            float bias = (o < 4) ? loadv(b_tm, o, f32) : loadv(b_tr, o - 4, f32);
            tl[o * 32 + px] = s + bias;
        }
        __syncthreads();
    }

    // ---- Stage B: geometry for 9 taps x 32 px ----
    for (int i = tid; i < 288; i += 512) {
        int k = i >> 5, ww2 = i & 31;
        float m00 = tl[ww2],       m01 = tl[32 + ww2];
        float m10 = tl[64 + ww2],  m11 = tl[96 + ww2];
        float tr0 = tl[128 + ww2], tr1 = tl[160 + ww2];
        float ry = (float)(k / 3) - 1.f;
        float rx = (float)(k % 3) - 1.f;
        float dy = m00 * ry + m01 * rx - ry + tr0;
        float dx = m10 * ry + m11 * rx - rx + tr1;
        float py = (float)h + ry + dy;
        float px = (float)(wb + ww2) + rx + dx;
        float y0f = floorf(py), x0f = floorf(px);
        g_y0[i] = (int)y0f; g_x0[i] = (int)x0f;
        g_wy[i] = py - y0f; g_wx[i] = px - x0f;
    }
    __syncthreads();

    // ---- Stage C: deep-pipelined K-loop ----
    // step s (0..71): k = s>>3, cb = s&7. Per step:
    //   ds_read B(s) | [c==5: ptrs k+1] | smp(s+3) | wload(s+2) |
    //   [c==7: cw k+1] | pub(s+1) | mfma(s) | barrier
    const int sw  = tid >> 4;      // px 0..31
    const int scq = tid & 15;      // channel pair
    const int o0  = wv << 5;

    floatx4 acc[2][2];
    #pragma unroll
    for (int i = 0; i < 2; ++i)
        #pragma unroll
        for (int j = 0; j < 2; ++j)
            acc[i][j] = (floatx4){0.f, 0.f, 0.f, 0.f};

    short* slw = &Sl[0][sw * 40 + (scq << 1)];             // +1280 shorts = slot1
    const short* slr = &Sl[0][l16 * 40 + (quad << 3)];     // +640 = j1, +1280 = slot1
    const int wlane = ((o0 + l16) << 5) + (quad << 3);     // per-lane weight offset
    const u16* wq = wTg;                                   // uniform, +8192/step

    const u16* p00; const u16* p01; const u16* p10; const u16* p11;
    float cw00, cw01, cw10, cw11;

    auto mkptr = [&](int k) {
        int gi = (k << 5) + sw;
        int y0 = g_y0[gi], x0 = g_x0[gi];
        int yc0 = min(max(y0, 0), 63),     yc1 = min(max(y0 + 1, 0), 63);
        int xc0 = min(max(x0, 0), 63),     xc1 = min(max(x0 + 1, 0), 63);
        const u16* bp = sp + (scq << 1);
        p00 = bp + (((yc0 << 6) + xc0) << 8);
        p01 = bp + (((yc0 << 6) + xc1) << 8);
        p10 = bp + (((yc1 << 6) + xc0) << 8);
        p11 = bp + (((yc1 << 6) + xc1) << 8);
    };
    auto mkcw = [&](int k) {
        int gi = (k << 5) + sw;
        int y0 = g_y0[gi], x0 = g_x0[gi];
        float wy1 = g_wy[gi], wx1 = g_wx[gi];
        float wy0 = 1.f - wy1, wx0 = 1.f - wx1;
        bool yv0 = (y0 >= 0) && (y0 < 64);
        bool yv1 = (y0 >= -1) && (y0 < 63);
        bool xv0 = (x0 >= 0) && (x0 < 64);
        bool xv1 = (x0 >= -1) && (x0 < 63);
        cw00 = (yv0 && xv0) ? wy0 * wx0 : 0.f;
        cw01 = (yv0 && xv1) ? wy0 * wx1 : 0.f;
        cw10 = (yv1 && xv0) ? wy1 * wx0 : 0.f;
        cw11 = (yv1 && xv1) ? wy1 * wx1 : 0.f;
    };

    u32 S[4][4];               // 4 rotating gather sets
    bf16x8 W0[4], W1[4];       // 4 rotating weight slots

    auto SMP = [&](int cb, int set) {      // cb, set compile-time after unroll
        S[set][0] = *(const u32*)(p00 + (cb << 5));
        S[set][1] = *(const u32*)(p01 + (cb << 5));
        S[set][2] = *(const u32*)(p10 + (cb << 5));
        S[set][3] = *(const u32*)(p11 + (cb << 5));
    };
    auto WLD = [&](int slot) {
        W0[slot] = *(const bf16x8*)(wq + wlane);
        W1[slot] = *(const bf16x8*)(wq + wlane + 512);
        wq += 8192;
    };
    auto PUB = [&](int set, int slot) {
        u32 r00 = S[set][0], r01 = S[set][1], r10 = S[set][2], r11 = S[set][3];
        float va = fmaf(cw00, bf2f((u16)r00),
                   fmaf(cw01, bf2f((u16)r01),
                   fmaf(cw10, bf2f((u16)r10), cw11 * bf2f((u16)r11))));
        float vb = fmaf(cw00, bf2f((u16)(r00 >> 16)),
                   fmaf(cw01, bf2f((u16)(r01 >> 16)),
                   fmaf(cw10, bf2f((u16)(r10 >> 16)), cw11 * bf2f((u16)(r11 >> 16)))));
        *(u32*)(slw + slot * 1280) = cvtpk(va, vb);
    };
    auto MFMA4 = [&](int ws, bf16x8 b0, bf16x8 b1) {
        acc[0][0] = __builtin_amdgcn_mfma_f32_16x16x32_bf16(W0[ws], b0, acc[0][0], 0, 0, 0);
        acc[1][0] = __builtin_amdgcn_mfma_f32_16x16x32_bf16(W1[ws], b0, acc[1][0], 0, 0, 0);
        acc[0][1] = __builtin_amdgcn_mfma_f32_16x16x32_bf16(W0[ws], b1, acc[0][1], 0, 0, 0);
        acc[1][1] = __builtin_amdgcn_mfma_f32_16x16x32_bf16(W1[ws], b1, acc[1][1], 0, 0, 0);
    };

    // prologue: sets t=0,1,2; weights t=0,1; publish t=0
    mkptr(0); mkcw(0);
    SMP(0, 0); SMP(1, 1); SMP(2, 2);
    WLD(0); WLD(1);
    PUB(0, 0);
    __syncthreads();

    // main: s = k8*8 + c, k8 = 0..7 (lookahead valid: k up to 8)
    for (int k8 = 0; k8 < 8; ++k8) {
        #pragma unroll
        for (int c = 0; c < 8; ++c) {
            const int sl = c & 1;
            bf16x8 b0 = *(const bf16x8*)(slr + sl * 1280);
            bf16x8 b1 = *(const bf16x8*)(slr + sl * 1280 + 640);
            if (c == 5) mkptr(k8 + 1);         // smp crosses into k8+1 at c>=5
            SMP((c + 3) & 7, (c + 3) & 3);
            WLD((c + 2) & 3);
            if (c == 7) mkcw(k8 + 1);          // pub crosses into k8+1 at c==7
            PUB((c + 1) & 3, (c + 1) & 1);
            MFMA4(c & 3, b0, b1);
            __syncthreads();
        }
    }
    // epilogue: k8 == 8 (s = 64..71), static drain guards
    #pragma unroll
    for (int c = 0; c < 8; ++c) {
        const int sl = c & 1;
        bf16x8 b0 = *(const bf16x8*)(slr + sl * 1280);
        bf16x8 b1 = *(const bf16x8*)(slr + sl * 1280 + 640);
        if (c < 5) SMP((c + 3) & 7, (c + 3) & 3);   // t = 67+c <= 71
        if (c < 6) WLD((c + 2) & 3);                // t = 66+c <= 71
        if (c < 7) PUB((c + 1) & 3, (c + 1) & 1);   // t = 65+c <= 71
        MFMA4(c & 3, b0, b1);
        if (c < 7) __syncthreads();
    }

    // ---- Stage D: GN partials (no atomics) ----
    #pragma unroll
    for (int i = 0; i < 2; ++i) {
        float s1 = 0.f, s2 = 0.f;
        #pragma unroll
        for (int j = 0; j < 2; ++j)
            #pragma unroll
            for (int r = 0; r < 4; ++r) {
                float v = acc[i][j][r];
                s1 += v; s2 += v * v;
            }
        #pragma unroll
        for (int off = 1; off <= 16; off <<= 1) {
            s1 += __shfl_xor(s1, off, 64);
            s2 += __shfl_xor(s2, off, 64);
        }
        if ((lane & 31) == 0) {
            int g = (o0 >> 3) + 2 * i + (lane >> 5);
            pstats[((long)bid << 6) + (g << 1)]     = s1;
            pstats[((long)bid << 6) + (g << 1) + 1] = s2;
        }
    }

    // ---- Stage E: raw stores ----
    #pragma unroll
    for (int i = 0; i < 2; ++i)
        #pragma unroll
        for (int j = 0; j < 2; ++j)
            #pragma unroll
            for (int r = 0; r < 4; ++r) {
                int o = o0 + i * 16 + quad * 4 + r;
                raw[nbase + ((long)o << 12) + (h << 6) + wb + (j << 4) + l16]
                    = f2bf(acc[i][j][r]);
            }
}

// ---------------------------------------------------------------------------
// GN + relu; reduces pstats, raw NCHW -> out1 NHWC (vectorized loads).
// ---------------------------------------------------------------------------
__global__ __launch_bounds__(256) void k_gn_relu(
    const u16* __restrict__ raw, const float* __restrict__ pstats,
    const void* __restrict__ gamma, const void* __restrict__ beta,
    const u32* __restrict__ xw,
    u16* __restrict__ out1)
{
    __shared__ u16 T[64 * 258];
    __shared__ float sred[4][64];
    __shared__ float sl[64];
    const int f32 = sniff_f32(xw);
    const int bid = blockIdx.x;
    const int n = bid >> 6, h = bid & 63;
    const int tid = threadIdx.x;

    {   // reduce partials: value v over 128 blocks of this n
        const int v = tid & 63, part = tid >> 6;
        float a = 0.f;
        for (int j = part * 32; j < part * 32 + 32; ++j)
            a += pstats[(((long)n * 128 + j) << 6) + v];
        sred[part][v] = a;
        __syncthreads();
        if (tid < 64) sl[tid] = sred[0][tid] + sred[1][tid] + sred[2][tid] + sred[3][tid];
        __syncthreads();
    }

    const u16* rb = raw + (long)n * CHW + (h << 6);
    const int cb = tid >> 3;         // 0..31
    const int w0 = (tid & 7) << 3;   // 0..56
    for (int it = 0; it < 8; ++it) {
        int c = (it << 5) + cb;
        int g = c >> 3;
        float mean = sl[g * 2] * (1.f / 32768.f);
        float var  = sl[g * 2 + 1] * (1.f / 32768.f) - mean * mean;
        float rstd = rsqrtf(var + 1e-5f);
        float ga = loadv(gamma, c, f32) * rstd;
        float be = loadv(beta, c, f32) - mean * ga;
        uint4 v = *(const uint4*)(rb + (long)c * HW + w0);
        u32 ws[4] = {v.x, v.y, v.z, v.w};
        #pragma unroll
        for (int q = 0; q < 4; ++q) {
            float a = fmaxf(fmaf(bf2f((u16)(ws[q] & 0xFFFFu)), ga, be), 0.f);
            float b = fmaxf(fmaf(bf2f((u16)(ws[q] >> 16)),     ga, be), 0.f);
            T[(w0 + 2 * q + 0) * 258 + c] = f2bf(a);
            T[(w0 + 2 * q + 1) * 258 + c] = f2bf(b);
        }
    }
    __syncthreads();
    const int w = tid >> 2, cq = tid & 3;
    const u32* Tr = (const u32*)T;
    u16* ob = out1 + (long)n * CHW + (long)((h << 6) + w) * 256 + cq * 64;
    #pragma unroll
    for (int s = 0; s < 8; ++s) {
        uint4 o;
        o.x = Tr[129 * w + 32 * cq + 4 * s + 0];
        o.y = Tr[129 * w + 32 * cq + 4 * s + 1];
        o.z = Tr[129 * w + 32 * cq + 4 * s + 2];
        o.w = Tr[129 * w + 32 * cq + 4 * s + 3];
        *(uint4*)&ob[s * 8] = o;
    }
}

// ---------------------------------------------------------------------------
// Final GN + residual + relu (per-block partial reduction).
// ---------------------------------------------------------------------------
__global__ __launch_bounds__(256) void k_gn_final(
    const u16* __restrict__ raw, const float* __restrict__ pstats,
    const void* __restrict__ gamma, const void* __restrict__ beta,
    const void* __restrict__ x,
    void* __restrict__ outp)
{
    __shared__ float rr[256];
    const int f32 = sniff_f32((const u32*)x);
    const int tid = threadIdx.x;
    const long e0 = ((long)blockIdx.x) << 11;
    const int n = (int)(e0 >> 20);
    const int c0 = (int)((e0 >> 12) & 255);
    const int g = c0 >> 3;

    {
        int j = tid & 127, sv = tid >> 7;
        rr[tid] = pstats[(((long)n * 128 + j) << 6) + (g << 1) + sv];
        __syncthreads();
        #pragma unroll
        for (int s = 64; s >= 1; s >>= 1) {
            if ((tid & 127) < s) rr[tid] += rr[tid + s];
            __syncthreads();
        }
    }
    float mean = rr[0] * (1.f / 32768.f);
    float var  = rr[128] * (1.f / 32768.f) - mean * mean;
    float rstd = rsqrtf(var + 1e-5f);

    const long i = blockIdx.x * 256 + tid;
    const long e = i << 3;
    const int c = (int)((e >> 12) & 255);
    float ga = loadv(gamma, c, f32) * rstd;
    float be = loadv(beta, c, f32) - mean * ga;
    uint4 p = ((const uint4*)raw)[i];
    u32 ww[4] = {p.x, p.y, p.z, p.w};
    float v[8];
    #pragma unroll
    for (int q = 0; q < 4; ++q) {
        v[2 * q + 0] = fmaxf(fmaf(bf2f((u16)(ww[q] & 0xFFFFu)), ga, be) + loadv(x, e + 2 * q + 0, f32), 0.f);
        v[2 * q + 1] = fmaxf(fmaf(bf2f((u16)(ww[q] >> 16)),     ga, be) + loadv(x, e + 2 * q + 1, f32), 0.f);
    }
    if (f32) {
        float4* op = (float4*)((float*)outp + e);
        op[0] = make_float4(v[0], v[1], v[2], v[3]);
        op[1] = make_float4(v[4], v[5], v[6], v[7]);
    } else {
        uint4 o;
        o.x = cvtpk(v[0], v[1]);
        o.y = cvtpk(v[2], v[3]);
        o.z = cvtpk(v[4], v[5]);
        o.w = cvtpk(v[6], v[7]);
        ((uint4*)outp)[i] = o;
    }
}

extern "C" void kernel_launch(void* const* d_in, const int* in_sizes, int n_in,
                              void* d_out, int out_size, void* d_ws, size_t ws_size,
                              hipStream_t stream) {
    const void* x     = d_in[0];
    const void* w_tm1 = d_in[1];
    const void* b_tm1 = d_in[2];
    const void* w_tr1 = d_in[3];
    const void* b_tr1 = d_in[4];
    const void* w_dc1 = d_in[5];
    const void* g1    = d_in[6];
    const void* be1   = d_in[7];
    const void* w_tm2 = d_in[8];
    const void* b_tm2 = d_in[9];
    const void* w_tr2 = d_in[10];
    const void* b_tr2 = d_in[11];
    const void* w_dc2 = d_in[12];
    const void* g2    = d_in[13];
    const void* be2   = d_in[14];

    char* wsb = (char*)d_ws;
    u16*   xT     = (u16*)wsb;                       // 8,388,608 (alias out1)
    u16*   raw    = (u16*)(wsb + 8388608);           // 8,388,608
    u16*   wTg1   = (u16*)(wsb + 16777216);          // 1,179,648
    u16*   wTg2   = (u16*)(wsb + 17956864);          // 1,179,648
    u16*   wT61   = (u16*)(wsb + 19136512);          //    73,728
    u16*   wT62   = (u16*)(wsb + 19210240);          //    73,728
    float* pstats = (float*)(wsb + 19283968);        //   131,072
    u16*   out1   = xT;
    const u32* xw = (const u32*)x;

    k_prep_all<<<2848, 256, 0, stream>>>(x, w_dc1, w_dc2, w_tm1, w_tr1, w_tm2, w_tr2,
                                         xT, wTg1, wTg2, wT61, wT62);
    // ---- round 1 ----
    k_deform  <<<512, 512, 0, stream>>>(xT, wTg1, wT61, b_tm1, b_tr1, xw, raw, pstats);
    k_gn_relu <<<256, 256, 0, stream>>>(raw, pstats, g1, be1, xw, out1);
    // ---- round 2 ----
    k_deform  <<<512, 512, 0, stream>>>(out1, wTg2, wT62, b_tm2, b_tr2, xw, raw, pstats);
    k_gn_final<<<2048, 256, 0, stream>>>(raw, pstats, g2, be2, x, d_out);
}

// Round 3
// 235.703 us; speedup vs baseline: 1.0675x; 1.0046x over previous
//
#include <hip/hip_runtime.h>

// v12: v11 + LIGHT BARRIERS in stage-C k-loop (T3/T4 counted-vmcnt).
// __syncthreads() drains vmcnt(0) (guide: barrier drain) -> destroyed the
// pipeline. Replaced with sched_barrier(0) + s_waitcnt lgkmcnt(0) +
// raw s_barrier: lgkm drained (LDS publish visibility, WAR-safe), vmcnt
// NEVER drained in-loop -> gather/weight loads stay in flight across steps.
// Rest identical to v11. 5 dispatches.
// ws (19,415,040 B): xT/out1 8MB | raw 8MB | wTg1 1.18MB | wTg2 1.18MB |
//   wT61 72KB | wT62 72KB | pstats 128KB

typedef unsigned int u32;
typedef unsigned short u16;
typedef __attribute__((ext_vector_type(8))) short bf16x8;
typedef __attribute__((ext_vector_type(4))) float floatx4;

#define HW 4096
#define CHW 1048576

static __device__ __forceinline__ float bf2f(u16 u) {
    union { u32 i; float f; } c; c.i = ((u32)u) << 16; return c.f;
}
static __device__ __forceinline__ u16 f2bf(float f) {
    union { float f; u32 i; } c; c.f = f;
    u32 x = c.i;
    return (u16)((x + 0x7FFFu + ((x >> 16) & 1u)) >> 16);   // RNE
}
// pack two f32 -> {lo: bf16(a), hi: bf16(b)} in ONE VALU op (RNE).
static __device__ __forceinline__ u32 cvtpk(float a, float b) {
    u32 r;
    asm("v_cvt_pk_bf16_f32 %0, %1, %2" : "=v"(r) : "v"(a), "v"(b));
    return r;
}
// Light barrier: drain LDS ops (publish visibility + WAR close), sync,
// do NOT drain vmcnt -> global loads stay in flight across the barrier.
static __device__ __forceinline__ void lbar() {
    __builtin_amdgcn_sched_barrier(0);
    asm volatile("s_waitcnt lgkmcnt(0)" ::: "memory");
    __builtin_amdgcn_s_barrier();
    __builtin_amdgcn_sched_barrier(0);
}
static __device__ __forceinline__ float loadv(const void* p, long i, int f32) {
    return f32 ? ((const float*)p)[i] : bf2f(((const u16*)p)[i]);
}
static __device__ __forceinline__ int sniff_f32(const u32* __restrict__ xw) {
    int cnt = 0;
    #pragma unroll
    for (int s = 0; s < 16; ++s) {
        union { u32 i; float f; } c;
        c.i = xw[s * 131 + 7];
        float a = fabsf(c.f);
        if (a > 1e-8f && a < 1e4f) ++cnt;
    }
    return (cnt >= 8) ? 1 : 0;
}

// ---------------------------------------------------------------------------
// One prep kernel: blocks [0,256) NCHW->NHWC transpose (vectorized);
// [256,1408) wTg1; [1408,2560) wTg2; [2560,2704) wT61; [2704,2848) wT62.
// ---------------------------------------------------------------------------
__global__ __launch_bounds__(256) void k_prep_all(
    const void* __restrict__ x,
    const void* __restrict__ wdc1, const void* __restrict__ wdc2,
    const void* __restrict__ wtm1, const void* __restrict__ wtr1,
    const void* __restrict__ wtm2, const void* __restrict__ wtr2,
    u16* __restrict__ xT, u16* __restrict__ wTg1, u16* __restrict__ wTg2,
    u16* __restrict__ wT61, u16* __restrict__ wT62)
{
    __shared__ u16 T[64 * 258];
    const int f32 = sniff_f32((const u32*)x);
    const int b = blockIdx.x;
    const int tid = threadIdx.x;

    if (b < 256) {                       // ---- NCHW -> NHWC (LDS transpose)
        const int n = b >> 6, h = b & 63;
        const long sb = (long)n * CHW + (h << 6);
        const int cb = tid >> 3;         // 0..31
        const int w0 = (tid & 7) << 3;   // 0..56
        if (f32) {
            const float* xp = (const float*)x;
            for (int it = 0; it < 8; ++it) {
                int c = (it << 5) + cb;
                const float* pr = xp + sb + (long)c * HW + w0;
                float4 a = ((const float4*)pr)[0];
                float4 d = ((const float4*)pr)[1];
                T[(w0 + 0) * 258 + c] = f2bf(a.x);
                T[(w0 + 1) * 258 + c] = f2bf(a.y);
                T[(w0 + 2) * 258 + c] = f2bf(a.z);
                T[(w0 + 3) * 258 + c] = f2bf(a.w);
                T[(w0 + 4) * 258 + c] = f2bf(d.x);
                T[(w0 + 5) * 258 + c] = f2bf(d.y);
                T[(w0 + 6) * 258 + c] = f2bf(d.z);
                T[(w0 + 7) * 258 + c] = f2bf(d.w);
            }
        } else {
            const u16* xp = (const u16*)x;
            for (int it = 0; it < 8; ++it) {
                int c = (it << 5) + cb;
                uint4 v = *(const uint4*)(xp + sb + (long)c * HW + w0);
                u32 ws[4] = {v.x, v.y, v.z, v.w};
                #pragma unroll
                for (int q = 0; q < 4; ++q) {
                    T[(w0 + 2 * q + 0) * 258 + c] = (u16)(ws[q] & 0xFFFFu);
                    T[(w0 + 2 * q + 1) * 258 + c] = (u16)(ws[q] >> 16);
                }
            }
        }
        __syncthreads();
        const int w = tid >> 2, cq = tid & 3;
        const u32* Tr = (const u32*)T;
        u16* ob = xT + (long)n * CHW + (long)((h << 6) + w) * 256 + cq * 64;
        #pragma unroll
        for (int s = 0; s < 8; ++s) {
            uint4 o;
            o.x = Tr[129 * w + 32 * cq + 4 * s + 0];
            o.y = Tr[129 * w + 32 * cq + 4 * s + 1];
            o.z = Tr[129 * w + 32 * cq + 4 * s + 2];
            o.w = Tr[129 * w + 32 * cq + 4 * s + 3];
            *(uint4*)&ob[s * 8] = o;
        }
    } else if (b < 2560) {               // ---- deform weights (both rounds)
        const int r2 = (b >= 1408);
        const void* wdc = r2 ? wdc2 : wdc1;
        u16* wTg = r2 ? wTg2 : wTg1;
        int idx2 = (b - (r2 ? 1408 : 256)) * 256 + tid;   // 0..294911
        int cp = idx2 & 15;
        int o  = (idx2 >> 4) & 255;
        int q  = idx2 >> 12;
        int k  = q >> 3;
        int c0 = ((q & 7) << 5) + (cp << 1);
        long s0 = (long)o * 2304 + c0 * 9 + k;
        ((u32*)wTg)[idx2] = cvtpk(loadv(wdc, s0, f32), loadv(wdc, s0 + 9, f32));
    } else {                             // ---- offset-conv weights
        const int r2 = (b >= 2704);
        const void* wtm = r2 ? wtm2 : wtm1;
        const void* wtr = r2 ? wtr2 : wtr1;
        u16* wT6 = r2 ? wT62 : wT61;
        int i = (b - (r2 ? 2704 : 2560)) * 256 + tid;     // 0..36863
        int q  = i >> 9;
        int o  = (i >> 5) & 15;
        int cc = i & 31;
        int k  = q >> 3;
        int c  = ((q & 7) << 5) + cc;
        float v = 0.f;
        if (o < 4)      v = loadv(wtm, (long)o * 2304 + c * 9 + k, f32);
        else if (o < 6) v = loadv(wtr, (long)(o - 4) * 2304 + c * 9 + k, f32);
        wT6[i] = f2bf(v);
    }
}

// ---------------------------------------------------------------------------
// Mega deform: per (n,h,half) block:
//   Stage A: offset conv (MFMA) -> tmtr slice in LDS
//   Stage B: build_offset geometry
//   Stage C: deep-pipelined K-loop with light barriers (counted vmcnt)
//   Stage D: GN partials -> pstats[bid][64]
//   Stage E: raw (NCHW bf16) stores
// ---------------------------------------------------------------------------
__global__ __launch_bounds__(512, 4) void k_deform(
    const u16* __restrict__ srcT, const u16* __restrict__ wTg,
    const u16* __restrict__ wT6,
    const void* __restrict__ b_tm, const void* __restrict__ b_tr,
    const u32* __restrict__ xw,
    u16* __restrict__ raw, float* __restrict__ pstats)
{
    __shared__ float red[8][32][17];                 // 17408 B (stage A)
    __shared__ float tl[6 * 32];                     //   768 B
    __shared__ __align__(16) short Sl[2][32 * 40];   //  5120 B
    __shared__ int   g_y0[288];
    __shared__ int   g_x0[288];
    __shared__ float g_wy[288];
    __shared__ float g_wx[288];

    const int tid = threadIdx.x;
    const int bid = blockIdx.x;                 // n*128 + h*2 + half
    const int n = bid >> 7, h = (bid >> 1) & 63, half = bid & 1;
    const int wb = half << 5;
    const int lane = tid & 63;
    const int quad = lane >> 4;
    const int l16  = lane & 15;
    const int wv   = tid >> 6;
    const long nbase = (long)n * CHW;
    const u16* sp = srcT + nbase;

    // ---- Stage A: offset conv, 6 out-ch x 32 px ----
    {
        floatx4 acc6[2];
        acc6[0] = (floatx4){0.f, 0.f, 0.f, 0.f};
        acc6[1] = (floatx4){0.f, 0.f, 0.f, 0.f};
        for (int qi = 0; qi < 9; ++qi) {
            const int q = wv * 9 + qi;
            const int k = q >> 3, cb = q & 7;
            const int ky = k / 3, kx = k % 3;
            const int row = h + ky - 1;
            const bool rv = (row >= 0) && (row < 64);
            bf16x8 av = *(const bf16x8*)&wT6[(((q << 4) + l16) << 5) + (quad << 3)];
            #pragma unroll
            for (int j = 0; j < 2; ++j) {
                int psrc = wb + (j << 4) + l16 + kx - 1;
                bf16x8 bv = {0, 0, 0, 0, 0, 0, 0, 0};
                if (rv && psrc >= 0 && psrc < 64)
                    bv = *(const bf16x8*)&sp[(((long)(row << 6) + psrc) << 8) + (cb << 5) + (quad << 3)];
                acc6[j] = __builtin_amdgcn_mfma_f32_16x16x32_bf16(av, bv, acc6[j], 0, 0, 0);
            }
        }
        #pragma unroll
        for (int j = 0; j < 2; ++j)
            #pragma unroll
            for (int r = 0; r < 4; ++r)
                red[wv][(j << 4) + l16][(quad << 2) + r] = acc6[j][r];
        __syncthreads();
        if (tid < 192) {
            const int o = tid >> 5, px = tid & 31;
            float s = 0.f;
            #pragma unroll
            for (int v = 0; v < 8; ++v) s += red[v][px][o];
            const int f32 = sniff_f32(xw);
            float bias = (o < 4) ? loadv(b_tm, o, f32) : loadv(b_tr, o - 4, f32);
            tl[o * 32 + px] = s + bias;
        }
        __syncthreads();
    }

    // ---- Stage B: geometry for 9 taps x 32 px ----
    for (int i = tid; i < 288; i += 512) {
        int k = i >> 5, ww2 = i & 31;
        float m00 = tl[ww2],       m01 = tl[32 + ww2];
        float m10 = tl[64 + ww2],  m11 = tl[96 + ww2];
        float tr0 = tl[128 + ww2], tr1 = tl[160 + ww2];
        float ry = (float)(k / 3) - 1.f;
        float rx = (float)(k % 3) - 1.f;
        float dy = m00 * ry + m01 * rx - ry + tr0;
        float dx = m10 * ry + m11 * rx - rx + tr1;
        float py = (float)h + ry + dy;
        float px = (float)(wb + ww2) + rx + dx;
        float y0f = floorf(py), x0f = floorf(px);
        g_y0[i] = (int)y0f; g_x0[i] = (int)x0f;
        g_wy[i] = py - y0f; g_wx[i] = px - x0f;
    }
    __syncthreads();

    // ---- Stage C: deep-pipelined K-loop ----
    // step s (0..71): k = s>>3, cb = s&7. Per step:
    //   ds_read B(s) | [c==5: ptrs k+1] | smp(s+3) | wload(s+2) |
    //   [c==7: cw k+1] | pub(s+1) | mfma(s) | light barrier
    const int sw  = tid >> 4;      // px 0..31
    const int scq = tid & 15;      // channel pair
    const int o0  = wv << 5;

    floatx4 acc[2][2];
    #pragma unroll
    for (int i = 0; i < 2; ++i)
        #pragma unroll
        for (int j = 0; j < 2; ++j)
            acc[i][j] = (floatx4){0.f, 0.f, 0.f, 0.f};

    short* slw = &Sl[0][sw * 40 + (scq << 1)];             // +1280 shorts = slot1
    const short* slr = &Sl[0][l16 * 40 + (quad << 3)];     // +640 = j1, +1280 = slot1
    const int wlane = ((o0 + l16) << 5) + (quad << 3);     // per-lane weight offset
    const u16* wq = wTg;                                   // uniform, +8192/step

    const u16* p00; const u16* p01; const u16* p10; const u16* p11;
    float cw00, cw01, cw10, cw11;

    auto mkptr = [&](int k) {
        int gi = (k << 5) + sw;
        int y0 = g_y0[gi], x0 = g_x0[gi];
        int yc0 = min(max(y0, 0), 63),     yc1 = min(max(y0 + 1, 0), 63);
        int xc0 = min(max(x0, 0), 63),     xc1 = min(max(x0 + 1, 0), 63);
        const u16* bp = sp + (scq << 1);
        p00 = bp + (((yc0 << 6) + xc0) << 8);
        p01 = bp + (((yc0 << 6) + xc1) << 8);
        p10 = bp + (((yc1 << 6) + xc0) << 8);
        p11 = bp + (((yc1 << 6) + xc1) << 8);
    };
    auto mkcw = [&](int k) {
        int gi = (k << 5) + sw;
        int y0 = g_y0[gi], x0 = g_x0[gi];
        float wy1 = g_wy[gi], wx1 = g_wx[gi];
        float wy0 = 1.f - wy1, wx0 = 1.f - wx1;
        bool yv0 = (y0 >= 0) && (y0 < 64);
        bool yv1 = (y0 >= -1) && (y0 < 63);
        bool xv0 = (x0 >= 0) && (x0 < 64);
        bool xv1 = (x0 >= -1) && (x0 < 63);
        cw00 = (yv0 && xv0) ? wy0 * wx0 : 0.f;
        cw01 = (yv0 && xv1) ? wy0 * wx1 : 0.f;
        cw10 = (yv1 && xv0) ? wy1 * wx0 : 0.f;
        cw11 = (yv1 && xv1) ? wy1 * wx1 : 0.f;
    };

    u32 S[4][4];               // 4 rotating gather sets
    bf16x8 W0[4], W1[4];       // 4 rotating weight slots

    auto SMP = [&](int cb, int set) {      // cb, set compile-time after unroll
        S[set][0] = *(const u32*)(p00 + (cb << 5));
        S[set][1] = *(const u32*)(p01 + (cb << 5));
        S[set][2] = *(const u32*)(p10 + (cb << 5));
        S[set][3] = *(const u32*)(p11 + (cb << 5));
    };
    auto WLD = [&](int slot) {
        W0[slot] = *(const bf16x8*)(wq + wlane);
        W1[slot] = *(const bf16x8*)(wq + wlane + 512);
        wq += 8192;
    };
    auto PUB = [&](int set, int slot) {
        u32 r00 = S[set][0], r01 = S[set][1], r10 = S[set][2], r11 = S[set][3];
        float va = fmaf(cw00, bf2f((u16)r00),
                   fmaf(cw01, bf2f((u16)r01),
                   fmaf(cw10, bf2f((u16)r10), cw11 * bf2f((u16)r11))));
        float vb = fmaf(cw00, bf2f((u16)(r00 >> 16)),
                   fmaf(cw01, bf2f((u16)(r01 >> 16)),
                   fmaf(cw10, bf2f((u16)(r10 >> 16)), cw11 * bf2f((u16)(r11 >> 16)))));
        *(u32*)(slw + slot * 1280) = cvtpk(va, vb);
    };
    auto MFMA4 = [&](int ws, bf16x8 b0, bf16x8 b1) {
        acc[0][0] = __builtin_amdgcn_mfma_f32_16x16x32_bf16(W0[ws], b0, acc[0][0], 0, 0, 0);
        acc[1][0] = __builtin_amdgcn_mfma_f32_16x16x32_bf16(W1[ws], b0, acc[1][0], 0, 0, 0);
        acc[0][1] = __builtin_amdgcn_mfma_f32_16x16x32_bf16(W0[ws], b1, acc[0][1], 0, 0, 0);
        acc[1][1] = __builtin_amdgcn_mfma_f32_16x16x32_bf16(W1[ws], b1, acc[1][1], 0, 0, 0);
    };

    // prologue: sets t=0,1,2; weights t=0,1; publish t=0
    mkptr(0); mkcw(0);
    SMP(0, 0); SMP(1, 1); SMP(2, 2);
    WLD(0); WLD(1);
    PUB(0, 0);
    lbar();

    // main: s = k8*8 + c, k8 = 0..7 (lookahead valid: k up to 8)
    for (int k8 = 0; k8 < 8; ++k8) {
        #pragma unroll
        for (int c = 0; c < 8; ++c) {
            const int sl = c & 1;
            bf16x8 b0 = *(const bf16x8*)(slr + sl * 1280);
            bf16x8 b1 = *(const bf16x8*)(slr + sl * 1280 + 640);
            if (c == 5) mkptr(k8 + 1);         // smp crosses into k8+1 at c>=5
            SMP((c + 3) & 7, (c + 3) & 3);
            WLD((c + 2) & 3);
            if (c == 7) mkcw(k8 + 1);          // pub crosses into k8+1 at c==7
            PUB((c + 1) & 3, (c + 1) & 1);
            MFMA4(c & 3, b0, b1);
            lbar();
        }
    }
    // epilogue: k8 == 8 (s = 64..71), static drain guards
    #pragma unroll
    for (int c = 0; c < 8; ++c) {
        const int sl = c & 1;
        bf16x8 b0 = *(const bf16x8*)(slr + sl * 1280);
        bf16x8 b1 = *(const bf16x8*)(slr + sl * 1280 + 640);
        if (c < 5) SMP((c + 3) & 7, (c + 3) & 3);   // t = 67+c <= 71
        if (c < 6) WLD((c + 2) & 3);                // t = 66+c <= 71
        if (c < 7) PUB((c + 1) & 3, (c + 1) & 1);   // t = 65+c <= 71
        MFMA4(c & 3, b0, b1);
        if (c < 7) lbar();
    }

    // ---- Stage D: GN partials (no atomics) ----
    #pragma unroll
    for (int i = 0; i < 2; ++i) {
        float s1 = 0.f, s2 = 0.f;
        #pragma unroll
        for (int j = 0; j < 2; ++j)
            #pragma unroll
            for (int r = 0; r < 4; ++r) {
                float v = acc[i][j][r];
                s1 += v; s2 += v * v;
            }
        #pragma unroll
        for (int off = 1; off <= 16; off <<= 1) {
            s1 += __shfl_xor(s1, off, 64);
            s2 += __shfl_xor(s2, off, 64);
        }
        if ((lane & 31) == 0) {
            int g = (o0 >> 3) + 2 * i + (lane >> 5);
            pstats[((long)bid << 6) + (g << 1)]     = s1;
            pstats[((long)bid << 6) + (g << 1) + 1] = s2;
        }
    }

    // ---- Stage E: raw stores ----
    #pragma unroll
    for (int i = 0; i < 2; ++i)
        #pragma unroll
        for (int j = 0; j < 2; ++j)
            #pragma unroll
            for (int r = 0; r < 4; ++r) {
                int o = o0 + i * 16 + quad * 4 + r;
                raw[nbase + ((long)o << 12) + (h << 6) + wb + (j << 4) + l16]
                    = f2bf(acc[i][j][r]);
            }
}

// ---------------------------------------------------------------------------
// GN + relu; reduces pstats, raw NCHW -> out1 NHWC (vectorized loads).
// ---------------------------------------------------------------------------
__global__ __launch_bounds__(256) void k_gn_relu(
    const u16* __restrict__ raw, const float* __restrict__ pstats,
    const void* __restrict__ gamma, const void* __restrict__ beta,
    const u32* __restrict__ xw,
    u16* __restrict__ out1)
{
    __shared__ u16 T[64 * 258];
    __shared__ float sred[4][64];
    __shared__ float sl[64];
    const int f32 = sniff_f32(xw);
    const int bid = blockIdx.x;
    const int n = bid >> 6, h = bid & 63;
    const int tid = threadIdx.x;

    {   // reduce partials: value v over 128 blocks of this n
        const int v = tid & 63, part = tid >> 6;
        float a = 0.f;
        for (int j = part * 32; j < part * 32 + 32; ++j)
            a += pstats[(((long)n * 128 + j) << 6) + v];
        sred[part][v] = a;
        __syncthreads();
        if (tid < 64) sl[tid] = sred[0][tid] + sred[1][tid] + sred[2][tid] + sred[3][tid];
        __syncthreads();
    }

    const u16* rb = raw + (long)n * CHW + (h << 6);
    const int cb = tid >> 3;         // 0..31
    const int w0 = (tid & 7) << 3;   // 0..56
    for (int it = 0; it < 8; ++it) {
        int c = (it << 5) + cb;
        int g = c >> 3;
        float mean = sl[g * 2] * (1.f / 32768.f);
        float var  = sl[g * 2 + 1] * (1.f / 32768.f) - mean * mean;
        float rstd = rsqrtf(var + 1e-5f);
        float ga = loadv(gamma, c, f32) * rstd;
        float be = loadv(beta, c, f32) - mean * ga;
        uint4 v = *(const uint4*)(rb + (long)c * HW + w0);
        u32 ws[4] = {v.x, v.y, v.z, v.w};
        #pragma unroll
        for (int q = 0; q < 4; ++q) {
            float a = fmaxf(fmaf(bf2f((u16)(ws[q] & 0xFFFFu)), ga, be), 0.f);
            float b = fmaxf(fmaf(bf2f((u16)(ws[q] >> 16)),     ga, be), 0.f);
            T[(w0 + 2 * q + 0) * 258 + c] = f2bf(a);
            T[(w0 + 2 * q + 1) * 258 + c] = f2bf(b);
        }
    }
    __syncthreads();
    const int w = tid >> 2, cq = tid & 3;
    const u32* Tr = (const u32*)T;
    u16* ob = out1 + (long)n * CHW + (long)((h << 6) + w) * 256 + cq * 64;
    #pragma unroll
    for (int s = 0; s < 8; ++s) {
        uint4 o;
        o.x = Tr[129 * w + 32 * cq + 4 * s + 0];
        o.y = Tr[129 * w + 32 * cq + 4 * s + 1];
        o.z = Tr[129 * w + 32 * cq + 4 * s + 2];
        o.w = Tr[129 * w + 32 * cq + 4 * s + 3];
        *(uint4*)&ob[s * 8] = o;
    }
}

// ---------------------------------------------------------------------------
// Final GN + residual + relu (per-block partial reduction).
// ---------------------------------------------------------------------------
__global__ __launch_bounds__(256) void k_gn_final(
    const u16* __restrict__ raw, const float* __restrict__ pstats,
    const void* __restrict__ gamma, const void* __restrict__ beta,
    const void* __restrict__ x,
    void* __restrict__ outp)
{
    __shared__ float rr[256];
    const int f32 = sniff_f32((const u32*)x);
    const int tid = threadIdx.x;
    const long e0 = ((long)blockIdx.x) << 11;
    const int n = (int)(e0 >> 20);
    const int c0 = (int)((e0 >> 12) & 255);
    const int g = c0 >> 3;

    {
        int j = tid & 127, sv = tid >> 7;
        rr[tid] = pstats[(((long)n * 128 + j) << 6) + (g << 1) + sv];
        __syncthreads();
        #pragma unroll
        for (int s = 64; s >= 1; s >>= 1) {
            if ((tid & 127) < s) rr[tid] += rr[tid + s];
            __syncthreads();
        }
    }
    float mean = rr[0] * (1.f / 32768.f);
    float var  = rr[128] * (1.f / 32768.f) - mean * mean;
    float rstd = rsqrtf(var + 1e-5f);

    const long i = blockIdx.x * 256 + tid;
    const long e = i << 3;
    const int c = (int)((e >> 12) & 255);
    float ga = loadv(gamma, c, f32) * rstd;
    float be = loadv(beta, c, f32) - mean * ga;
    uint4 p = ((const uint4*)raw)[i];
    u32 ww[4] = {p.x, p.y, p.z, p.w};
    float v[8];
    #pragma unroll
    for (int q = 0; q < 4; ++q) {
        v[2 * q + 0] = fmaxf(fmaf(bf2f((u16)(ww[q] & 0xFFFFu)), ga, be) + loadv(x, e + 2 * q + 0, f32), 0.f);
        v[2 * q + 1] = fmaxf(fmaf(bf2f((u16)(ww[q] >> 16)),     ga, be) + loadv(x, e + 2 * q + 1, f32), 0.f);
    }
    if (f32) {
        float4* op = (float4*)((float*)outp + e);
        op[0] = make_float4(v[0], v[1], v[2], v[3]);
        op[1] = make_float4(v[4], v[5], v[6], v[7]);
    } else {
        uint4 o;
        o.x = cvtpk(v[0], v[1]);
        o.y = cvtpk(v[2], v[3]);
        o.z = cvtpk(v[4], v[5]);
        o.w = cvtpk(v[6], v[7]);
        ((uint4*)outp)[i] = o;
    }
}

extern "C" void kernel_launch(void* const* d_in, const int* in_sizes, int n_in,
                              void* d_out, int out_size, void* d_ws, size_t ws_size,
                              hipStream_t stream) {
    const void* x     = d_in[0];
    const void* w_tm1 = d_in[1];
    const void* b_tm1 = d_in[2];
    const void* w_tr1 = d_in[3];
    const void* b_tr1 = d_in[4];
    const void* w_dc1 = d_in[5];
    const void* g1    = d_in[6];
    const void* be1   = d_in[7];
    const void* w_tm2 = d_in[8];
    const void* b_tm2 = d_in[9];
    const void* w_tr2 = d_in[10];
    const void* b_tr2 = d_in[11];
    const void* w_dc2 = d_in[12];
    const void* g2    = d_in[13];
    const void* be2   = d_in[14];

    char* wsb = (char*)d_ws;
    u16*   xT     = (u16*)wsb;                       // 8,388,608 (alias out1)
    u16*   raw    = (u16*)(wsb + 8388608);           // 8,388,608
    u16*   wTg1   = (u16*)(wsb + 16777216);          // 1,179,648
    u16*   wTg2   = (u16*)(wsb + 17956864);          // 1,179,648
    u16*   wT61   = (u16*)(wsb + 19136512);          //    73,728
    u16*   wT62   = (u16*)(wsb + 19210240);          //    73,728
    float* pstats = (float*)(wsb + 19283968);        //   131,072
    u16*   out1   = xT;
    const u32* xw = (const u32*)x;

    k_prep_all<<<2848, 256, 0, stream>>>(x, w_dc1, w_dc2, w_tm1, w_tr1, w_tm2, w_tr2,
                                         xT, wTg1, wTg2, wT61, wT62);
    // ---- round 1 ----
    k_deform  <<<512, 512, 0, stream>>>(xT, wTg1, wT61, b_tm1, b_tr1, xw, raw, pstats);
    k_gn_relu <<<256, 256, 0, stream>>>(raw, pstats, g1, be1, xw, out1);
    // ---- round 2 ----
    k_deform  <<<512, 512, 0, stream>>>(out1, wTg2, wT62, b_tm2, b_tr2, xw, raw, pstats);
    k_gn_final<<<2048, 256, 0, stream>>>(raw, pstats, g2, be2, x, d_out);
}